// Round 1
// baseline (157.119 us; speedup 1.0000x reference)
//
#include <hip/hip_runtime.h>

// PairwiseRankLoss: U=262144 users x G=64 items, K=2, MARGIN=0.3
// One 64-lane wave per user. Bitonic sort for exact median order stats,
// ballot-argmax for top-2 rand selection per side (tie-break = lowest index,
// matching lax.top_k). Deterministic two-stage reduction via d_ws.

static constexpr int kUsers = 262144;
static constexpr int kBlock = 256;                  // 4 waves / block
static constexpr int kGrid  = 2048;                 // 8 blocks / CU
static constexpr int kWavesPerBlock = kBlock / 64;
static constexpr int kTotalWaves = kGrid * kWavesPerBlock;  // 8192 -> 32 users/wave
static constexpr float kMargin = 0.3f;

__global__ __launch_bounds__(kBlock, 8)
void prl_user_kernel(const float* __restrict__ y_hat,
                     const float* __restrict__ y_true,
                     const float* __restrict__ rnd,
                     float* __restrict__ partials)
{
    const int lane = threadIdx.x & 63;
    const int wid  = (blockIdx.x * kBlock + threadIdx.x) >> 6;

    float acc = 0.0f;

    for (int u = wid; u < kUsers; u += kTotalWaves) {
        const int base = (u << 6) + lane;
        const float yh = y_hat[base];
        const float yt = y_true[base];
        const float r  = rnd[base];

        // ---- bitonic sort of yt across 64 lanes, ascending ----
        float v = yt;
        #pragma unroll
        for (int k = 2; k <= 64; k <<= 1) {
            #pragma unroll
            for (int j = k >> 1; j > 0; j >>= 1) {
                const float p = __shfl_xor(v, j);
                const bool keepmin = (((lane & k) == 0) == ((lane & j) == 0));
                v = ((v < p) == keepmin) ? v : p;
            }
        }
        const float a31 = __shfl(v, 31);   // 32nd smallest
        const float a32 = __shfl(v, 32);   // 33rd smallest
        const float med = 0.5f * (a31 + a32);
        const bool pos  = (yt > med);      // bit-exact vs reference mask

        // ---- top-2 rand per side; gather y_hat of winners ----
        float P0, P1, N0, N1;
        #pragma unroll
        for (int side = 0; side < 2; ++side) {
            const bool m = side == 0 ? pos : !pos;
            float key = m ? r : -2.0f;     // r in [0,1): -2 acts as -inf
            float mx = key;
            #pragma unroll
            for (int s = 32; s > 0; s >>= 1) mx = fmaxf(mx, __shfl_xor(mx, s));
            unsigned long long b = __ballot(key == mx);
            const int l1 = __builtin_ctzll(b);       // lowest index on ties
            const float A0 = __shfl(yh, l1);
            if (lane == l1) key = -3.0f;             // exclude winner
            float mx2 = key;
            #pragma unroll
            for (int s = 32; s > 0; s >>= 1) mx2 = fmaxf(mx2, __shfl_xor(mx2, s));
            b = __ballot(key == mx2);
            const int l2 = __builtin_ctzll(b);
            const float A1 = __shfl(yh, l2);
            if (side == 0) { P0 = A0; P1 = A1; }
            else           { N0 = A0; N1 = A1; }
        }

        // ---- 2x2 hinge mean ----
        float s = 0.0f;
        s += fmaxf(kMargin - (P0 - N0), 0.0f);
        s += fmaxf(kMargin - (P0 - N1), 0.0f);
        s += fmaxf(kMargin - (P1 - N0), 0.0f);
        s += fmaxf(kMargin - (P1 - N1), 0.0f);
        acc += 0.25f * s;
    }

    // block partial (acc is wave-uniform; take lane 0 of each wave)
    __shared__ float wsum[kWavesPerBlock];
    if (lane == 0) wsum[threadIdx.x >> 6] = acc;
    __syncthreads();
    if (threadIdx.x == 0) {
        float t = 0.0f;
        #pragma unroll
        for (int i = 0; i < kWavesPerBlock; ++i) t += wsum[i];
        partials[blockIdx.x] = t;
    }
}

__global__ void prl_reduce_kernel(const float* __restrict__ partials,
                                  float* __restrict__ out)
{
    // one block of 256 threads reduces kGrid partials in a fixed order
    float t = 0.0f;
    for (int i = threadIdx.x; i < kGrid; i += 256) t += partials[i];
    #pragma unroll
    for (int s = 32; s > 0; s >>= 1) t += __shfl_xor(t, s);
    __shared__ float ws[4];
    if ((threadIdx.x & 63) == 0) ws[threadIdx.x >> 6] = t;
    __syncthreads();
    if (threadIdx.x == 0) {
        out[0] = (ws[0] + ws[1] + ws[2] + ws[3]) * (1.0f / (float)kUsers);
    }
}

extern "C" void kernel_launch(void* const* d_in, const int* in_sizes, int n_in,
                              void* d_out, int out_size, void* d_ws, size_t ws_size,
                              hipStream_t stream) {
    const float* y_hat  = (const float*)d_in[0];
    const float* y_true = (const float*)d_in[1];
    const float* rnd    = (const float*)d_in[2];
    // d_in[3] = user_idx: contiguous equal-size segments -> never read
    float* partials = (float*)d_ws;          // kGrid floats = 8 KiB scratch
    float* out      = (float*)d_out;

    hipLaunchKernelGGL(prl_user_kernel, dim3(kGrid), dim3(kBlock), 0, stream,
                       y_hat, y_true, rnd, partials);
    hipLaunchKernelGGL(prl_reduce_kernel, dim3(1), dim3(256), 0, stream,
                       partials, out);
}

// Round 2
// 133.910 us; speedup vs baseline: 1.1733x; 1.1733x over previous
//
#include <hip/hip_runtime.h>

// PairwiseRankLoss: U=262144 users x G=64 items, K=2, MARGIN=0.3
// One 64-lane wave per user; 4 users interleaved per iteration for ILP.
// Bitonic sort for exact median order stats, ballot-argmax + readlane for
// top-2 rand selection per side (tie-break = lowest index, matching
// lax.top_k). Deterministic two-stage reduction via d_ws.

static constexpr int kUsers = 262144;
static constexpr int kBlock = 256;                  // 4 waves / block
static constexpr int kGrid  = 2048;                 // 8 blocks / CU
static constexpr int kWavesPerBlock = kBlock / 64;
static constexpr int kTotalWaves = kGrid * kWavesPerBlock;  // 8192
static constexpr int kUsersPerWave = kUsers / kTotalWaves;  // 32
static constexpr int kUPW = 4;                      // users interleaved / iter
static constexpr int kIters = kUsersPerWave / kUPW; // 8
static constexpr float kMargin = 0.3f;

static __device__ __forceinline__ float readlane_f(float x, int l) {
    return __uint_as_float(__builtin_amdgcn_readlane(__float_as_uint(x), l));
}

__global__ __launch_bounds__(kBlock, 8)
void prl_user_kernel(const float* __restrict__ y_hat,
                     const float* __restrict__ y_true,
                     const float* __restrict__ rnd,
                     float* __restrict__ partials)
{
    const int lane = threadIdx.x & 63;
    const int wid  = (blockIdx.x * kBlock + threadIdx.x) >> 6;

    float acc = 0.0f;

    #pragma unroll 1
    for (int it = 0; it < kIters; ++it) {
        const int u0 = wid * kUsersPerWave + it * kUPW;

        float yh[kUPW], yt[kUPW], r[kUPW], v[kUPW];
        #pragma unroll
        for (int q = 0; q < kUPW; ++q) {
            const int base = ((u0 + q) << 6) + lane;
            yh[q] = y_hat[base];
            yt[q] = y_true[base];
            r[q]  = rnd[base];
            v[q]  = yt[q];
        }

        // ---- bitonic sort of yt across 64 lanes, ascending (x4 interleaved)
        #pragma unroll
        for (int k = 2; k <= 64; k <<= 1) {
            #pragma unroll
            for (int j = k >> 1; j > 0; j >>= 1) {
                const bool keepmin = (((lane & k) == 0) == ((lane & j) == 0));
                #pragma unroll
                for (int q = 0; q < kUPW; ++q) {
                    const float p = __shfl_xor(v[q], j);
                    v[q] = ((v[q] < p) == keepmin) ? v[q] : p;
                }
            }
        }

        bool pos[kUPW];
        #pragma unroll
        for (int q = 0; q < kUPW; ++q) {
            const float a31 = readlane_f(v[q], 31);   // 32nd smallest
            const float a32 = readlane_f(v[q], 32);   // 33rd smallest
            const float med = 0.5f * (a31 + a32);
            pos[q] = (yt[q] > med);                   // bit-exact mask
        }

        // ---- top-2 rand per side; gather y_hat of winners (x4 interleaved)
        float P0[kUPW], P1[kUPW], N0[kUPW], N1[kUPW];
        #pragma unroll
        for (int side = 0; side < 2; ++side) {
            float key[kUPW], mx[kUPW];
            #pragma unroll
            for (int q = 0; q < kUPW; ++q) {
                const bool m = (side == 0) ? pos[q] : !pos[q];
                key[q] = m ? r[q] : -2.0f;            // r in [0,1): -2 = -inf
                mx[q]  = key[q];
            }
            #pragma unroll
            for (int s = 32; s > 0; s >>= 1) {
                #pragma unroll
                for (int q = 0; q < kUPW; ++q)
                    mx[q] = fmaxf(mx[q], __shfl_xor(mx[q], s));
            }
            int l1[kUPW];
            #pragma unroll
            for (int q = 0; q < kUPW; ++q) {
                const unsigned long long b = __ballot(key[q] == mx[q]);
                l1[q] = __builtin_ctzll(b);           // lowest index on ties
                const float A0 = readlane_f(yh[q], l1[q]);
                if (side == 0) P0[q] = A0; else N0[q] = A0;
                if (lane == l1[q]) key[q] = -3.0f;    // exclude winner
                mx[q] = key[q];
            }
            #pragma unroll
            for (int s = 32; s > 0; s >>= 1) {
                #pragma unroll
                for (int q = 0; q < kUPW; ++q)
                    mx[q] = fmaxf(mx[q], __shfl_xor(mx[q], s));
            }
            #pragma unroll
            for (int q = 0; q < kUPW; ++q) {
                const unsigned long long b = __ballot(key[q] == mx[q]);
                const int l2 = __builtin_ctzll(b);
                const float A1 = readlane_f(yh[q], l2);
                if (side == 0) P1[q] = A1; else N1[q] = A1;
            }
        }

        // ---- 2x2 hinge mean ----
        #pragma unroll
        for (int q = 0; q < kUPW; ++q) {
            float s = 0.0f;
            s += fmaxf(kMargin - (P0[q] - N0[q]), 0.0f);
            s += fmaxf(kMargin - (P0[q] - N1[q]), 0.0f);
            s += fmaxf(kMargin - (P1[q] - N0[q]), 0.0f);
            s += fmaxf(kMargin - (P1[q] - N1[q]), 0.0f);
            acc += 0.25f * s;
        }
    }

    // block partial (acc is wave-uniform; take lane 0 of each wave)
    __shared__ float wsum[kWavesPerBlock];
    if (lane == 0) wsum[threadIdx.x >> 6] = acc;
    __syncthreads();
    if (threadIdx.x == 0) {
        float t = 0.0f;
        #pragma unroll
        for (int i = 0; i < kWavesPerBlock; ++i) t += wsum[i];
        partials[blockIdx.x] = t;
    }
}

__global__ void prl_reduce_kernel(const float* __restrict__ partials,
                                  float* __restrict__ out)
{
    // one block of 256 threads reduces kGrid partials in a fixed order
    float t = 0.0f;
    for (int i = threadIdx.x; i < kGrid; i += 256) t += partials[i];
    #pragma unroll
    for (int s = 32; s > 0; s >>= 1) t += __shfl_xor(t, s);
    __shared__ float ws[4];
    if ((threadIdx.x & 63) == 0) ws[threadIdx.x >> 6] = t;
    __syncthreads();
    if (threadIdx.x == 0) {
        out[0] = (ws[0] + ws[1] + ws[2] + ws[3]) * (1.0f / (float)kUsers);
    }
}

extern "C" void kernel_launch(void* const* d_in, const int* in_sizes, int n_in,
                              void* d_out, int out_size, void* d_ws, size_t ws_size,
                              hipStream_t stream) {
    const float* y_hat  = (const float*)d_in[0];
    const float* y_true = (const float*)d_in[1];
    const float* rnd    = (const float*)d_in[2];
    // d_in[3] = user_idx: contiguous equal-size segments -> never read
    float* partials = (float*)d_ws;          // kGrid floats = 8 KiB scratch
    float* out      = (float*)d_out;

    hipLaunchKernelGGL(prl_user_kernel, dim3(kGrid), dim3(kBlock), 0, stream,
                       y_hat, y_true, rnd, partials);
    hipLaunchKernelGGL(prl_reduce_kernel, dim3(1), dim3(256), 0, stream,
                       partials, out);
}